// Round 2
// baseline (62378.540 us; speedup 1.0000x reference)
//
#include <hip/hip_runtime.h>
#include <math.h>

// Problem constants (match reference)
#define BATCH  256
#define SEQT   256
#define FEATD  256
#define NHEADS 8
#define HD     32
#define HID    512
#define GATES  2048           // 4*HID
#define BH     (BATCH*HID)    // 131072 floats per [B,HID] slab
#define TOUT   (SEQT-1)       // 255 output time steps

__device__ __forceinline__ float sigm(float x)     { return 1.f / (1.f + __expf(-x)); }
__device__ __forceinline__ float tanhfast(float x) { return 1.f - 2.f / (1.f + __expf(2.f * x)); }

// ---------------------------------------------------------------------------
// Zero-init recurrent state each call (ws poisoned 0xAA once, never restored).
// h0 parity-1 slab = h0(-1)=0; h1 parity-1 slab = h1(-1)=0; c0=c1=0.
// ---------------------------------------------------------------------------
__global__ void k_zero(float* __restrict__ h0, float* __restrict__ h1,
                       float* __restrict__ c0, float* __restrict__ c1)
{
    int idx = blockIdx.x * 256 + threadIdx.x;
    if (idx < BH) {
        h0[BH + idx] = 0.f;
        h1[BH + idx] = 0.f;
        c0[idx] = 0.f;
        c1[idx] = 0.f;
    }
}

// ---------------------------------------------------------------------------
// Fused per-(n,h) attention: q regs, K/V in LDS (two 128-row tiles),
// online softmax, out = attn @ V. Energy scale 1/sqrt(FEAT)=1/16.
// Output written T-MAJOR: attn_t[t][n][f].
// grid = B*NHEADS blocks of 256 threads; thread = query row t.
// ---------------------------------------------------------------------------
__global__ __launch_bounds__(256) void k_attn(
    const float* __restrict__ x,  const float* __restrict__ wq,
    const float* __restrict__ wk, const float* __restrict__ wv,
    float* __restrict__ attn_t)
{
    __shared__ float Ks[128][40];
    __shared__ float Vs[128][40];

    const int nb  = blockIdx.x;
    const int n   = nb >> 3, h = nb & 7;
    const int tid = threadIdx.x;
    const float* xbase = x + ((size_t)n * SEQT) * FEATD + h * HD;

    float qv[HD];
    {
        float xr[HD];
        const float4* xp = (const float4*)(xbase + (size_t)tid * FEATD);
        #pragma unroll
        for (int q4 = 0; q4 < 8; ++q4) {
            float4 v = xp[q4];
            xr[q4*4+0] = v.x; xr[q4*4+1] = v.y; xr[q4*4+2] = v.z; xr[q4*4+3] = v.w;
        }
        #pragma unroll
        for (int d = 0; d < HD; ++d) {
            float s = 0.f;
            #pragma unroll
            for (int e = 0; e < HD; ++e) s += xr[e] * wq[d*HD + e];
            qv[d] = s * 0.0625f;
        }
    }

    float o[HD];
    #pragma unroll
    for (int d = 0; d < HD; ++d) o[d] = 0.f;
    float m = -1e30f, ssum = 0.f;

    for (int tile = 0; tile < 2; ++tile) {
        const int j0 = tile * 128;
        __syncthreads();
        {   // waves 0-1 -> K rows, waves 2-3 -> V rows (wave-uniform branch)
            const int r = tid & 127;
            const float* W = (tid < 128) ? wk : wv;
            float xt[HD];
            const float4* xp = (const float4*)(xbase + (size_t)(j0 + r) * FEATD);
            #pragma unroll
            for (int q4 = 0; q4 < 8; ++q4) {
                float4 v = xp[q4];
                xt[q4*4+0] = v.x; xt[q4*4+1] = v.y; xt[q4*4+2] = v.z; xt[q4*4+3] = v.w;
            }
            float outr[HD];
            #pragma unroll
            for (int d = 0; d < HD; ++d) {
                float s = 0.f;
                #pragma unroll
                for (int e = 0; e < HD; ++e) s += xt[e] * W[d*HD + e];
                outr[d] = s;
            }
            float (*dst)[40] = (tid < 128) ? Ks : Vs;
            #pragma unroll
            for (int d = 0; d < HD; ++d) dst[r][d] = outr[d];
        }
        __syncthreads();

        for (int j = 0; j < 128; ++j) {
            float e = 0.f;
            #pragma unroll
            for (int dq = 0; dq < 8; ++dq) {
                float4 kq = *(const float4*)&Ks[j][dq*4];
                e += qv[dq*4+0]*kq.x + qv[dq*4+1]*kq.y
                   + qv[dq*4+2]*kq.z + qv[dq*4+3]*kq.w;
            }
            if (e > m) {
                float sc = __expf(m - e);
                ssum *= sc;
                #pragma unroll
                for (int d = 0; d < HD; ++d) o[d] *= sc;
                m = e;
            }
            float p = __expf(e - m);
            ssum += p;
            #pragma unroll
            for (int dq = 0; dq < 8; ++dq) {
                float4 vq = *(const float4*)&Vs[j][dq*4];
                o[dq*4+0] += p * vq.x; o[dq*4+1] += p * vq.y;
                o[dq*4+2] += p * vq.z; o[dq*4+3] += p * vq.w;
            }
        }
    }

    const float inv = 1.f / ssum;
    float* ob = attn_t + ((size_t)tid * BATCH + n) * FEATD + h * HD;  // t-major
    #pragma unroll
    for (int dq = 0; dq < 8; ++dq) {
        float4 v;
        v.x = o[dq*4+0]*inv; v.y = o[dq*4+1]*inv;
        v.z = o[dq*4+2]*inv; v.w = o[dq*4+3]*inv;
        *(float4*)&ob[dq*4] = v;
    }
}

// ---------------------------------------------------------------------------
// Wc = w_hid @ w_fc [512,256]; bc = w_hid @ b_fc + b_hid
// ---------------------------------------------------------------------------
__global__ __launch_bounds__(256) void k_wcomb(
    const float* __restrict__ w_fc,  const float* __restrict__ b_fc,
    const float* __restrict__ w_hid, const float* __restrict__ b_hid,
    float* __restrict__ Wc, float* __restrict__ bc)
{
    const int i = blockIdx.x, j = threadIdx.x;
    float s = 0.f;
    for (int k = 0; k < FEATD; ++k) s += w_hid[i*FEATD + k] * w_fc[k*FEATD + j];
    Wc[(size_t)i*FEATD + j] = s;
    if (j == 0) {
        float t = b_hid[i];
        for (int k = 0; k < FEATD; ++k) t += w_hid[i*FEATD + k] * b_fc[k];
        bc[i] = t;
    }
}

// ---------------------------------------------------------------------------
// Wx0 = W_ih[0] @ Wc [2048,256]; bx0 = W_ih[0] @ bc + b_ih[0] + b_hh[0]
// Folds the xc GEMM into the layer-0 input weight (exact algebra).
// ---------------------------------------------------------------------------
__global__ __launch_bounds__(256) void k_wx0(
    const float* __restrict__ w_ih, const float* __restrict__ Wc,
    const float* __restrict__ bc,   const float* __restrict__ b_ih,
    const float* __restrict__ b_hh,
    float* __restrict__ Wx0, float* __restrict__ bx0)
{
    const int i = blockIdx.x, j = threadIdx.x;   // i<2048, j<256
    float s = 0.f;
    for (int k = 0; k < HID; ++k) s += w_ih[(size_t)i*HID + k] * Wc[(size_t)k*FEATD + j];
    Wx0[(size_t)i*FEATD + j] = s;
    if (j == 0) {
        float t = b_ih[i] + b_hh[i];
        for (int k = 0; k < HID; ++k) t += w_ih[(size_t)i*HID + k] * bc[k];
        bx0[i] = t;
    }
}

// ---------------------------------------------------------------------------
// LSTM step. fused=1: blocks [0,128)=layer1(t), [128,256)=layer0(t+1)
// (independent -> layer pipelining). fused=0: prologue layer0(0), grid 128.
// Layer0 ph0 reads attn_t directly through Wx0 (K=256); ph1 h0@Whh0 (K=512).
// Layer1: h0(t)@Wih1 + h1(t-1)@Whh1 (K=512+512).
// Fused projection: layer1 blocks with tile&31==0 compute
// ypred[:,t-1,:] = relu(h1(t-1))@w_out^T + b_out from staged hprev.
// ---------------------------------------------------------------------------
__global__ __launch_bounds__(256) void k_step(
    const float* __restrict__ attn_t, const float* __restrict__ Wx0,
    const float* __restrict__ bx0,
    float* __restrict__ h0, float* __restrict__ h1,
    float* __restrict__ c0, float* __restrict__ c1,
    const float* __restrict__ w_ih, const float* __restrict__ w_hh,
    const float* __restrict__ b_ih, const float* __restrict__ b_hh,
    const float* __restrict__ w_out, const float* __restrict__ b_out,
    float* __restrict__ out, int t, int fused)
{
    __shared__ float xs[64][33];
    int lay, tile;
    const float *x0src, *x1src, *W0, *W1;
    int K0;
    float *cbuf, *hout;
    bool doproj = false;

    if (!fused) {                               // prologue: layer0(0)
        lay = 0; tile = blockIdx.x;
        x0src = attn_t;                      K0 = FEATD;  W0 = Wx0;
        x1src = h0 + BH;                     W1 = w_hh;   // h0(-1)=0
        cbuf = c0; hout = h0;                               // parity 0
    } else if (blockIdx.x < 128) {              // layer1(t)
        lay = 1; tile = blockIdx.x;
        x0src = h0 + (size_t)(t & 1) * BH;   K0 = HID;
        W0 = w_ih + (size_t)GATES * HID;
        x1src = h1 + (size_t)((t & 1) ^ 1) * BH;            // h1(t-1)
        W1 = w_hh + (size_t)GATES * HID;
        cbuf = c1; hout = h1 + (size_t)(t & 1) * BH;
        doproj = (t > 0) && ((tile & 31) == 0);
    } else {                                    // layer0(t+1)
        const int tt = t + 1;
        if (tt > SEQT - 2) return;              // only steps 0..T-2 needed
        lay = 0; tile = blockIdx.x - 128;
        x0src = attn_t + (size_t)tt * BATCH * FEATD;  K0 = FEATD;  W0 = Wx0;
        x1src = h0 + (size_t)(t & 1) * BH;            W1 = w_hh;
        cbuf = c0; hout = h0 + (size_t)(tt & 1) * BH;
    }

    const int r0  = (tile >> 5) * 64;
    const int hc0 = (tile & 31) * 16;
    const int tid = threadIdx.x;
    const int hcl = tid & 15, rq = tid >> 4;
    const int hc  = hc0 + hcl;

    float acc[4][4] = {};       // [row i][gate g]
    float yacc0 = 0.f, yacc1 = 0.f;
    const int prow = tid >> 2, pj = (tid & 3) * 2;   // proj mapping: 64r x 8j

    #pragma unroll
    for (int ph = 0; ph < 2; ++ph) {
        const float* src = ph ? x1src : x0src;
        const float* W   = ph ? W1    : W0;
        const int Kp     = ph ? HID   : K0;
        for (int k0 = 0; k0 < Kp; k0 += 32) {
            __syncthreads();
            for (int idx = tid; idx < 64*32; idx += 256) {
                int r = idx >> 5, kk = idx & 31;
                xs[r][kk] = src[(size_t)(r0 + r) * Kp + k0 + kk];
            }
            __syncthreads();
            #pragma unroll
            for (int kq = 0; kq < 8; ++kq) {
                float4 wvv[4];
                #pragma unroll
                for (int g = 0; g < 4; ++g)
                    wvv[g] = *(const float4*)&W[(size_t)(g*HID + hc) * Kp + k0 + kq*4];
                #pragma unroll
                for (int ks = 0; ks < 4; ++ks) {
                    const int kk = kq*4 + ks;
                    #pragma unroll
                    for (int i = 0; i < 4; ++i) {
                        const float xv = xs[rq*4 + i][kk];
                        acc[i][0] += xv * ((const float*)&wvv[0])[ks];
                        acc[i][1] += xv * ((const float*)&wvv[1])[ks];
                        acc[i][2] += xv * ((const float*)&wvv[2])[ks];
                        acc[i][3] += xv * ((const float*)&wvv[3])[ks];
                    }
                }
            }
            if (doproj && ph == 1) {    // xs holds h1(t-1) rows -> project
                float a0 = 0.f, a1 = 0.f;
                #pragma unroll
                for (int kk = 0; kk < 32; ++kk) {
                    float hv = xs[prow][kk];
                    hv = hv > 0.f ? hv : 0.f;
                    a0 += hv * w_out[(size_t)pj     * HID + k0 + kk];
                    a1 += hv * w_out[(size_t)(pj+1) * HID + k0 + kk];
                }
                yacc0 += a0; yacc1 += a1;
            }
        }
    }

    float bsum[4];
    if (lay == 0) {
        #pragma unroll
        for (int g = 0; g < 4; ++g) bsum[g] = bx0[g*HID + hc];
    } else {
        #pragma unroll
        for (int g = 0; g < 4; ++g)
            bsum[g] = b_ih[GATES + g*HID + hc] + b_hh[GATES + g*HID + hc];
    }

    #pragma unroll
    for (int i = 0; i < 4; ++i) {
        const int r = r0 + rq*4 + i;
        const float gi = sigm(acc[i][0] + bsum[0]);
        const float gf = sigm(acc[i][1] + bsum[1]);
        const float gg = tanhfast(acc[i][2] + bsum[2]);
        const float go = sigm(acc[i][3] + bsum[3]);
        const size_t idx = (size_t)r * HID + hc;
        const float cn = gf * cbuf[idx] + gi * gg;
        cbuf[idx] = cn;
        hout[idx] = go * tanhfast(cn);
    }

    if (doproj) {
        const int n = r0 + prow, tt = t - 1;
        float* op = out + (size_t)n * (TOUT * NHEADS) + (size_t)tt * NHEADS;
        op[pj]   = yacc0 + b_out[pj];
        op[pj+1] = yacc1 + b_out[pj+1];
    }
}

// ---------------------------------------------------------------------------
// Tail projection for tt=254 from h1(254) (parity 0 slab passed directly).
// grid 8 x 256: idx = n*8 + j.
// ---------------------------------------------------------------------------
__global__ __launch_bounds__(256) void k_proj_tail(
    const float* __restrict__ h1p0, const float* __restrict__ w_out,
    const float* __restrict__ b_out, float* __restrict__ out)
{
    const int idx = blockIdx.x * 256 + threadIdx.x;
    const int j = idx & 7, n = idx >> 3;
    const float* hrow = h1p0 + (size_t)n * HID;
    float s = b_out[j];
    for (int k = 0; k < HID; ++k) {
        float hv = hrow[k];
        hv = hv > 0.f ? hv : 0.f;
        s += hv * w_out[(size_t)j * HID + k];
    }
    out[(size_t)n * (TOUT * NHEADS) + (size_t)(TOUT - 1) * NHEADS + j] = s;
}

// ---------------------------------------------------------------------------
extern "C" void kernel_launch(void* const* d_in, const int* in_sizes, int n_in,
                              void* d_out, int out_size, void* d_ws, size_t ws_size,
                              hipStream_t stream)
{
    (void)in_sizes; (void)n_in; (void)out_size; (void)ws_size;
    const float* x     = (const float*)d_in[0];
    const float* wq    = (const float*)d_in[1];
    const float* wk    = (const float*)d_in[2];
    const float* wv    = (const float*)d_in[3];
    const float* w_fc  = (const float*)d_in[4];
    const float* b_fc  = (const float*)d_in[5];
    const float* w_hid = (const float*)d_in[6];
    const float* b_hid = (const float*)d_in[7];
    const float* w_ih  = (const float*)d_in[8];
    const float* w_hh  = (const float*)d_in[9];
    const float* b_ih  = (const float*)d_in[10];
    const float* b_hh  = (const float*)d_in[11];
    const float* w_out = (const float*)d_in[12];
    const float* b_out = (const float*)d_in[13];

    float* ws = (float*)d_ws;
    size_t off = 0;
    float* attn_t = ws + off; off += (size_t)SEQT * BATCH * FEATD;  // 16.78M (t-major)
    float* Wc     = ws + off; off += (size_t)HID * FEATD;           // 131K
    float* bc     = ws + off; off += HID;
    float* Wx0    = ws + off; off += (size_t)GATES * FEATD;         // 524K
    float* bx0    = ws + off; off += GATES;
    float* h0     = ws + off; off += 2 * (size_t)BH;                // ping-pong
    float* h1     = ws + off; off += 2 * (size_t)BH;                // ping-pong
    float* c0     = ws + off; off += (size_t)BH;
    float* c1     = ws + off; off += (size_t)BH;
    // total ~18.22M floats = ~72.9 MB

    k_zero  <<<dim3(512),          dim3(256), 0, stream>>>(h0, h1, c0, c1);
    k_attn  <<<dim3(BATCH*NHEADS), dim3(256), 0, stream>>>(x, wq, wk, wv, attn_t);
    k_wcomb <<<dim3(HID),          dim3(256), 0, stream>>>(w_fc, b_fc, w_hid, b_hid, Wc, bc);
    k_wx0   <<<dim3(GATES),        dim3(256), 0, stream>>>(w_ih, Wc, bc, b_ih, b_hh, Wx0, bx0);

    // prologue: layer0(t=0)
    k_step <<<dim3(128), dim3(256), 0, stream>>>(attn_t, Wx0, bx0, h0, h1, c0, c1,
                                                 w_ih, w_hh, b_ih, b_hh,
                                                 w_out, b_out, (float*)d_out, 0, 0);
    // pipelined: layer1(t) || layer0(t+1), t = 0..T-2
    for (int t = 0; t <= SEQT - 2; ++t)
        k_step <<<dim3(256), dim3(256), 0, stream>>>(attn_t, Wx0, bx0, h0, h1, c0, c1,
                                                     w_ih, w_hh, b_ih, b_hh,
                                                     w_out, b_out, (float*)d_out, t, 1);

    k_proj_tail <<<dim3(8), dim3(256), 0, stream>>>(h1, w_out, b_out, (float*)d_out);
}